// Round 5
// baseline (554.883 us; speedup 1.0000x reference)
//
#include <hip/hip_runtime.h>
#include <math.h>

#define B 8
#define C 3
#define H 1024
#define W 1024
#define L 1024
#define D 512
#define DH 128
#define NPIX (H * W)
#define NOISY_ELEMS (B * C * NPIX) // 25165824
#define TH 16                      // rows per strip in fused kernel
#define SEGW 512                   // columns per block (W split in 2)
#define SROW (SEGW + 24)           // staged floats: 12 halo + 512 + 12 halo

typedef float vf4 __attribute__((ext_vector_type(4)));

struct BlurW { float w[21]; };

// ---------------- kernel 1: partial column sums of bottleneck_feat ----------
__global__ __launch_bounds__(256) void colsum_kernel(
        const float* __restrict__ feat, float* __restrict__ partial) {
    int blk = blockIdx.x;            // 0..511
    int b = blk >> 6, chunk = blk & 63;
    const float* base = feat + (size_t)b * (L * D) + (size_t)chunk * 16 * D;
    int t = threadIdx.x;             // 256
    float s0 = 0.f, s1 = 0.f;
    for (int ll = 0; ll < 16; ++ll) {
        s0 += base[ll * D + t];
        s1 += base[ll * D + t + 256];
    }
    float* dst = partial + (size_t)blk * D;
    dst[t] = s0;
    dst[t + 256] = s1;
}

// ---------------- kernel 2: MLP head -> alpha/beta --------------------------
__global__ void head_kernel(const float* __restrict__ partial,
                            const float* __restrict__ W1, const float* __restrict__ b1,
                            const float* __restrict__ ln_g, const float* __restrict__ ln_b,
                            const float* __restrict__ W2, const float* __restrict__ b2,
                            float* __restrict__ ab, float* __restrict__ out_tail) {
    const int b = blockIdx.x;
    const int j = threadIdx.x;   // 0..127
    __shared__ float fm[D];
    __shared__ float red[DH];
    for (int d = j; d < D; d += DH) {
        float s = 0.f;
        const float* p = partial + (size_t)b * 64 * D + d;
        for (int c = 0; c < 64; ++c) s += p[c * D];
        fm[d] = s * (1.0f / (float)L);
    }
    __syncthreads();
    float h = b1[j];
    const vf4* fm4 = (const vf4*)fm;
    #pragma unroll 8
    for (int d4 = 0; d4 < D / 4; ++d4) {
        vf4 f = fm4[d4];
        h = fmaf(f.x, W1[(4 * d4 + 0) * DH + j], h);
        h = fmaf(f.y, W1[(4 * d4 + 1) * DH + j], h);
        h = fmaf(f.z, W1[(4 * d4 + 2) * DH + j], h);
        h = fmaf(f.w, W1[(4 * d4 + 3) * DH + j], h);
    }

    red[j] = h; __syncthreads();
    for (int s = 64; s > 0; s >>= 1) { if (j < s) red[j] += red[j + s]; __syncthreads(); }
    float mu = red[0] * (1.f / (float)DH);
    __syncthreads();
    float hc = h - mu;
    red[j] = hc * hc; __syncthreads();
    for (int s = 64; s > 0; s >>= 1) { if (j < s) red[j] += red[j + s]; __syncthreads(); }
    float var = red[0] * (1.f / (float)DH);
    __syncthreads();

    float hn = hc * rsqrtf(var + 1e-5f) * ln_g[j] + ln_b[j];
    hn = fmaxf(hn, 0.f);

    red[j] = hn * W2[j * 2 + 0]; __syncthreads();
    for (int s = 64; s > 0; s >>= 1) { if (j < s) red[j] += red[j + s]; __syncthreads(); }
    float p0 = red[0];
    __syncthreads();
    red[j] = hn * W2[j * 2 + 1]; __syncthreads();
    for (int s = 64; s > 0; s >>= 1) { if (j < s) red[j] += red[j + s]; __syncthreads(); }
    float p1 = red[0];

    if (j == 0) {
        float a  = 0.00015f / (1.f + expf(-(p0 + b2[0])));
        float be = 0.00015f / (1.f + expf(-(p1 + b2[1])));
        ab[b] = a; ab[8 + b] = be;
        out_tail[b] = a; out_tail[8 + b] = be;
    }
}

// ---------------- kernel 3: fully fused hblur + vblur + synth ---------------
// grid: B * 64 strips * 2 half-widths = 1024 blocks, 256 threads.
// Thread t owns columns {x0+t, x0+256+t}. Mask rows staged to LDS
// (double-buffered), hblur'd on the fly into a 21-deep register window
// (stride-1 LDS reads -> conflict-free). Kernel symmetry halves blur FMAs.
__global__ __launch_bounds__(256, 4) void fused_final(
        const float* __restrict__ x_bg, const float* __restrict__ noise,
        const float* __restrict__ mask, const float* __restrict__ ab,
        float* __restrict__ out, BlurW kw) {
    int blk = blockIdx.x;            // 0..1023
    int b   = blk >> 7;
    int rem = blk & 127;
    int s   = rem >> 1;
    int wj  = rem & 1;
    int h0  = s * TH;
    int t   = threadIdx.x;           // 0..255
    int x0  = wj * SEGW;

    __shared__ float buf[2][SROW];
    const float* mbase = mask + (size_t)b * NPIX;

#define STAGE(P, HY) do {                                            \
        const float* row_ = mbase + (size_t)(HY) * W;                \
        _Pragma("unroll")                                            \
        for (int i_ = t; i_ < SROW; i_ += 256) {                     \
            int col_ = x0 + i_ - 12;                                 \
            buf[P][i_] = (col_ >= 0 && col_ < W) ? row_[col_] : 0.f; \
        }                                                            \
    } while (0)

#define HBLUR(P, DA, DB) do {                                              \
        const float* sp_ = buf[P];                                         \
        float aA_ = 0.f, aB_ = 0.f;                                        \
        _Pragma("unroll")                                                  \
        for (int k_ = 0; k_ < 10; ++k_) {                                  \
            aA_ = fmaf(kw.w[k_], sp_[t + 2 + k_] + sp_[t + 22 - k_], aA_); \
            aB_ = fmaf(kw.w[k_], sp_[t + 258 + k_] + sp_[t + 278 - k_], aB_); \
        }                                                                  \
        DA = fmaf(kw.w[10], sp_[t + 12], aA_);                             \
        DB = fmaf(kw.w[10], sp_[t + 268], aB_);                            \
    } while (0)

    float winA[21], winB[21];

    // prologue: rows h0-10 .. h0+10  (hy >= H impossible here)
    #pragma unroll
    for (int k = 0; k < 21; ++k) {
        int hy = h0 - 10 + k;
        if (hy >= 0) {                       // block-uniform
            STAGE(k & 1, hy);
            __syncthreads();
            HBLUR(k & 1, winA[k], winB[k]);
        } else { winA[k] = 0.f; winB[k] = 0.f; }
    }

    float alpha = ab[b], beta = ab[8 + b];

    #pragma unroll
    for (int r = 0; r < TH; ++r) {
        float msA = 0.f, msB = 0.f;
        #pragma unroll
        for (int k = 0; k < 10; ++k) {
            msA = fmaf(kw.w[k], winA[(r + k) % 21] + winA[(r + 20 - k) % 21], msA);
            msB = fmaf(kw.w[k], winB[(r + k) % 21] + winB[(r + 20 - k) % 21], msB);
        }
        msA = fmaf(kw.w[10], winA[(r + 10) % 21], msA);
        msB = fmaf(kw.w[10], winB[(r + 10) % 21], msB);

        int h = h0 + r;
        #pragma unroll
        for (int c = 0; c < C; ++c) {
            size_t idx = (((size_t)(b * C + c) * H) + h) * W + x0 + t;
            float xA = __builtin_nontemporal_load(x_bg + idx);
            float xB = __builtin_nontemporal_load(x_bg + idx + 256);
            float nA = __builtin_nontemporal_load(noise + idx);
            float nB = __builtin_nontemporal_load(noise + idx + 256);
            float sgA = sqrtf(fmaxf(fmaf(alpha, xA, beta), 1e-7f));
            float sgB = sqrtf(fmaxf(fmaf(alpha, xB, beta), 1e-7f));
            float oA = fmaf(1.5f * nA * sgA, msA, xA);
            float oB = fmaf(1.5f * nB * sgB, msB, xB);
            __builtin_nontemporal_store(oA, out + idx);
            __builtin_nontemporal_store(oB, out + idx + 256);
        }

        if (r < TH - 1) {
            int hy = h + 11;
            int slot = r % 21;
            if (hy < H) {                    // block-uniform; invalid only as suffix
                STAGE((21 + r) & 1, hy);
                __syncthreads();
                HBLUR((21 + r) & 1, winA[slot], winB[slot]);
            } else { winA[slot] = 0.f; winB[slot] = 0.f; }
        }
    }
#undef STAGE
#undef HBLUR
}

extern "C" void kernel_launch(void* const* d_in, const int* in_sizes, int n_in,
                              void* d_out, int out_size, void* d_ws, size_t ws_size,
                              hipStream_t stream) {
    const float* x_bg = (const float*)d_in[0];
    const float* feat = (const float*)d_in[1];
    const float* mask = (const float*)d_in[2];
    const float* noise = (const float*)d_in[3];
    const float* W1 = (const float*)d_in[4];
    const float* b1 = (const float*)d_in[5];
    const float* ln_g = (const float*)d_in[6];
    const float* ln_b = (const float*)d_in[7];
    const float* W2 = (const float*)d_in[8];
    const float* b2 = (const float*)d_in[9];
    float* out = (float*)d_out;

    // ws layout (floats): [0, 262144) partial colsums | [262144, +16) ab
    float* ws_f = (float*)d_ws;
    float* partial = ws_f;                       // B*64*D = 262144 floats
    float* ab = ws_f + 262144;                   // 16 floats

    BlurW kw;
    {
        double g[21], s = 0.0;
        for (int i = 0; i < 21; ++i) { double x = (double)(i - 10); g[i] = exp(-x * x / 50.0); s += g[i]; }
        for (int i = 0; i < 21; ++i) kw.w[i] = (float)(g[i] / s);
    }

    colsum_kernel<<<512, 256, 0, stream>>>(feat, partial);
    head_kernel<<<B, 128, 0, stream>>>(partial, W1, b1, ln_g, ln_b, W2, b2,
                                       ab, out + NOISY_ELEMS);
    fused_final<<<B * 64 * 2, 256, 0, stream>>>(x_bg, noise, mask, ab, out, kw);
}

// Round 6
// 133.857 us; speedup vs baseline: 4.1453x; 4.1453x over previous
//
#include <hip/hip_runtime.h>
#include <math.h>

#define B 8
#define C 3
#define H 1024
#define W 1024
#define L 1024
#define D 512
#define DH 128
#define NPIX (H * W)
#define NOISY_ELEMS (B * C * NPIX) // 25165824
#define TH 32                      // rows per strip in fused kernel
#define SEG 512                    // columns per block (W split in 2)
#define HALO 10
#define SROW2 (SEG + 2 * HALO)     // 532 staged floats per row
#define SPAD 544                   // padded LDS row

typedef float vf2 __attribute__((ext_vector_type(2)));
typedef float vf4 __attribute__((ext_vector_type(4)));

struct BlurW { float w[21]; };

// ---------------- kernel 1: partial column sums of bottleneck_feat ----------
__global__ __launch_bounds__(256) void colsum_kernel(
        const float* __restrict__ feat, float* __restrict__ partial) {
    int blk = blockIdx.x;            // 0..511
    int b = blk >> 6, chunk = blk & 63;
    const float* base = feat + (size_t)b * (L * D) + (size_t)chunk * 16 * D;
    int t = threadIdx.x;             // 256
    float s0 = 0.f, s1 = 0.f;
    for (int ll = 0; ll < 16; ++ll) {
        s0 += base[ll * D + t];
        s1 += base[ll * D + t + 256];
    }
    float* dst = partial + (size_t)blk * D;
    dst[t] = s0;
    dst[t + 256] = s1;
}

// ---------------- kernel 2: MLP head -> alpha/beta --------------------------
__global__ void head_kernel(const float* __restrict__ partial,
                            const float* __restrict__ W1, const float* __restrict__ b1,
                            const float* __restrict__ ln_g, const float* __restrict__ ln_b,
                            const float* __restrict__ W2, const float* __restrict__ b2,
                            float* __restrict__ ab, float* __restrict__ out_tail) {
    const int b = blockIdx.x;
    const int j = threadIdx.x;   // 0..127
    __shared__ float fm[D];
    __shared__ float red[DH];
    for (int d = j; d < D; d += DH) {
        float s = 0.f;
        const float* p = partial + (size_t)b * 64 * D + d;
        for (int c = 0; c < 64; ++c) s += p[c * D];
        fm[d] = s * (1.0f / (float)L);
    }
    __syncthreads();
    float h = b1[j];
    const vf4* fm4 = (const vf4*)fm;
    #pragma unroll 8
    for (int d4 = 0; d4 < D / 4; ++d4) {
        vf4 f = fm4[d4];
        h = fmaf(f.x, W1[(4 * d4 + 0) * DH + j], h);
        h = fmaf(f.y, W1[(4 * d4 + 1) * DH + j], h);
        h = fmaf(f.z, W1[(4 * d4 + 2) * DH + j], h);
        h = fmaf(f.w, W1[(4 * d4 + 3) * DH + j], h);
    }

    red[j] = h; __syncthreads();
    for (int s = 64; s > 0; s >>= 1) { if (j < s) red[j] += red[j + s]; __syncthreads(); }
    float mu = red[0] * (1.f / (float)DH);
    __syncthreads();
    float hc = h - mu;
    red[j] = hc * hc; __syncthreads();
    for (int s = 64; s > 0; s >>= 1) { if (j < s) red[j] += red[j + s]; __syncthreads(); }
    float var = red[0] * (1.f / (float)DH);
    __syncthreads();

    float hn = hc * rsqrtf(var + 1e-5f) * ln_g[j] + ln_b[j];
    hn = fmaxf(hn, 0.f);

    red[j] = hn * W2[j * 2 + 0]; __syncthreads();
    for (int s = 64; s > 0; s >>= 1) { if (j < s) red[j] += red[j + s]; __syncthreads(); }
    float p0 = red[0];
    __syncthreads();
    red[j] = hn * W2[j * 2 + 1]; __syncthreads();
    for (int s = 64; s > 0; s >>= 1) { if (j < s) red[j] += red[j + s]; __syncthreads(); }
    float p1 = red[0];

    if (j == 0) {
        float a  = 0.00015f / (1.f + expf(-(p0 + b2[0])));
        float be = 0.00015f / (1.f + expf(-(p1 + b2[1])));
        ab[b] = a; ab[8 + b] = be;
        out_tail[b] = a; out_tail[8 + b] = be;
    }
}

// ---------------- kernel 3: fused hblur + vblur + synth ---------------------
// grid: B * 32 strips * 2 half-widths = 512 blocks, 256 threads.
// Thread t owns 2 adjacent columns (x0+2t, x0+2t+1). 21-row hblurred window
// in vf2 registers, maintained by explicit unrolled shift (all-literal
// indices -> guaranteed register residency; outer row loop NOT unrolled).
// One barrier per staged row; double-buffered LDS raw-mask row.
__global__ __launch_bounds__(256) void fused_final(
        const float* __restrict__ x_bg, const float* __restrict__ noise,
        const float* __restrict__ mask, const float* __restrict__ ab,
        float* __restrict__ out, BlurW kw) {
    int blk = blockIdx.x;            // 0..511
    int b   = blk >> 6;
    int rem = blk & 63;
    int s   = rem >> 1;              // 0..31
    int wj  = rem & 1;
    int h0  = s * TH;
    int x0  = wj * SEG;
    int t   = threadIdx.x;           // 0..255

    __shared__ float buf[2][SPAD];
    const float* mbase = mask + (size_t)b * NPIX;

    float g0, g1, g2;
#define LOADROW(HY) do {                                              \
        int hy_ = (HY);                                               \
        if (hy_ >= 0 && hy_ < H) {   /* block-uniform */              \
            const float* rp_ = mbase + (size_t)hy_ * W;               \
            int c0_ = x0 - HALO + t;                                  \
            g0 = (c0_ >= 0) ? rp_[c0_] : 0.f;                         \
            g1 = rp_[c0_ + 256];     /* always in [246,1013] */       \
            int c2_ = c0_ + 512;                                      \
            g2 = (t < SROW2 - 512 && c2_ < W) ? rp_[c2_] : 0.f;       \
        } else { g0 = 0.f; g1 = 0.f; g2 = 0.f; }                      \
    } while (0)

#define WRITEROW(P) do {                                              \
        buf[P][t] = g0; buf[P][t + 256] = g1;                         \
        if (t < SROW2 - 512) buf[P][t + 512] = g2;                    \
    } while (0)

    // hblur of staged row in buf[P] -> vf2 HB (cols x0+2t, x0+2t+1)
#define HBLURROW(P, HB) do {                                          \
        float vv[22];                                                 \
        const float* sp_ = buf[P] + 2 * t;                            \
        _Pragma("unroll")                                             \
        for (int j = 0; j < 11; ++j) {                                \
            vf2 mm_ = *(const vf2*)(sp_ + 2 * j);                     \
            vv[2 * j] = mm_.x; vv[2 * j + 1] = mm_.y;                 \
        }                                                             \
        float ax_ = 0.f, ay_ = 0.f;                                   \
        _Pragma("unroll")                                             \
        for (int j = 0; j < 10; ++j) {                                \
            ax_ = fmaf(kw.w[j], vv[j] + vv[20 - j], ax_);             \
            ay_ = fmaf(kw.w[j], vv[j + 1] + vv[21 - j], ay_);         \
        }                                                             \
        HB.x = fmaf(kw.w[10], vv[10], ax_);                           \
        HB.y = fmaf(kw.w[10], vv[11], ay_);                           \
    } while (0)

    vf2 win[21];
    int p = 0;

    // prologue: stage row h0-10, then fill win[0..20] = hblur(rows h0-10..h0+10)
    LOADROW(h0 - 10);
    WRITEROW(0);
    __syncthreads();
    #pragma unroll
    for (int k = 0; k < 21; ++k) {
        LOADROW(h0 - 9 + k);             // next row
        HBLURROW(p, win[k]);
        WRITEROW(p ^ 1);
        __syncthreads();
        p ^= 1;
    }
    // invariant: buf[p] holds raw row h0+11

    float alpha = ab[b], beta = ab[8 + b];

    for (int r = 0; r < TH; ++r) {
        int h = h0 + r;
        bool stage = (r < TH - 1);
        if (stage) LOADROW(h + 12);      // issue early; consumed at loop bottom

        // vertical blur (symmetric) from register window
        float mx = 0.f, my = 0.f;
        #pragma unroll
        for (int k = 0; k < 10; ++k) {
            mx = fmaf(kw.w[k], win[k].x + win[20 - k].x, mx);
            my = fmaf(kw.w[k], win[k].y + win[20 - k].y, my);
        }
        mx = fmaf(kw.w[10], win[10].x, mx);
        my = fmaf(kw.w[10], win[10].y, my);

        // elementwise synth, 3 channels, dwordx2 per channel
        #pragma unroll
        for (int c = 0; c < C; ++c) {
            size_t idx = (((size_t)(b * C + c) * H) + h) * W + x0 + 2 * t;
            vf2 x = __builtin_nontemporal_load((const vf2*)(x_bg + idx));
            vf2 nz = __builtin_nontemporal_load((const vf2*)(noise + idx));
            vf2 o;
            float sgx = sqrtf(fmaxf(fmaf(alpha, x.x, beta), 1e-7f));
            float sgy = sqrtf(fmaxf(fmaf(alpha, x.y, beta), 1e-7f));
            o.x = fmaf(1.5f * nz.x * sgx, mx, x.x);
            o.y = fmaf(1.5f * nz.y * sgy, my, x.y);
            __builtin_nontemporal_store(o, (vf2*)(out + idx));
        }

        if (stage) {
            vf2 nw;
            HBLURROW(p, nw);             // row h+11
            #pragma unroll
            for (int i = 0; i < 20; ++i) win[i] = win[i + 1];
            win[20] = nw;
            WRITEROW(p ^ 1);             // row h+12
            __syncthreads();
            p ^= 1;
        }
    }
#undef LOADROW
#undef WRITEROW
#undef HBLURROW
}

extern "C" void kernel_launch(void* const* d_in, const int* in_sizes, int n_in,
                              void* d_out, int out_size, void* d_ws, size_t ws_size,
                              hipStream_t stream) {
    const float* x_bg = (const float*)d_in[0];
    const float* feat = (const float*)d_in[1];
    const float* mask = (const float*)d_in[2];
    const float* noise = (const float*)d_in[3];
    const float* W1 = (const float*)d_in[4];
    const float* b1 = (const float*)d_in[5];
    const float* ln_g = (const float*)d_in[6];
    const float* ln_b = (const float*)d_in[7];
    const float* W2 = (const float*)d_in[8];
    const float* b2 = (const float*)d_in[9];
    float* out = (float*)d_out;

    // ws layout (floats): [0, 262144) partial colsums | [262144, +16) ab
    float* ws_f = (float*)d_ws;
    float* partial = ws_f;                       // B*64*D = 262144 floats
    float* ab = ws_f + 262144;                   // 16 floats

    BlurW kw;
    {
        double g[21], s = 0.0;
        for (int i = 0; i < 21; ++i) { double x = (double)(i - 10); g[i] = exp(-x * x / 50.0); s += g[i]; }
        for (int i = 0; i < 21; ++i) kw.w[i] = (float)(g[i] / s);
    }

    colsum_kernel<<<512, 256, 0, stream>>>(feat, partial);
    head_kernel<<<B, 128, 0, stream>>>(partial, W1, b1, ln_g, ln_b, W2, b2,
                                       ab, out + NOISY_ELEMS);
    fused_final<<<B * 32 * 2, 256, 0, stream>>>(x_bg, noise, mask, ab, out, kw);
}

// Round 7
// 104.666 us; speedup vs baseline: 5.3015x; 1.2789x over previous
//
#include <hip/hip_runtime.h>
#include <math.h>

#define B 8
#define C 3
#define H 1024
#define W 1024
#define L 1024
#define D 512
#define DH 128
#define NPIX (H * W)
#define NOISY_ELEMS (B * C * NPIX) // 25165824
#define TH 16                      // rows per strip in final kernel

typedef float vf2 __attribute__((ext_vector_type(2)));
typedef float vf4 __attribute__((ext_vector_type(4)));

struct BlurW { float w[21]; };

// ---------------- kernel 1: fused horizontal blur + colsum ------------------
// blocks [0, 8192): one hblur image row each.
// blocks [8192, 8704): colsum partial sums of bottleneck_feat.
__global__ __launch_bounds__(256) void hblur_colsum_kernel(
        const float* __restrict__ mask, float* __restrict__ hmask,
        const float* __restrict__ feat, float* __restrict__ partial, BlurW kw) {
    int wgid = blockIdx.x;
    int t = threadIdx.x;             // 256
    __shared__ float srow[W + 24];   // data at [12 .. 12+W-1], zero halo 10/side

    if (wgid < 8192) {
        int l = wgid;
        const float* src = mask + (size_t)l * W;
        if (t < 10) { srow[2 + t] = 0.f; srow[12 + W + t] = 0.f; }
        vf4 v = __builtin_nontemporal_load((const vf4*)src + t);
        ((vf4*)(srow + 12))[t] = v;
        __syncthreads();
        float* dst = hmask + (size_t)l * W;
        #pragma unroll
        for (int i = 0; i < 4; ++i) {
            int x = t + 256 * i;
            float acc = 0.f;
            #pragma unroll
            for (int k = 0; k < 10; ++k)
                acc = fmaf(kw.w[k], srow[x + 2 + k] + srow[x + 22 - k], acc);
            acc = fmaf(kw.w[10], srow[x + 12], acc);
            dst[x] = acc;
        }
    } else {
        int blk = wgid - 8192;       // 0..511
        int b = blk >> 6, chunk = blk & 63;
        const float* base = feat + (size_t)b * (L * D) + (size_t)chunk * 16 * D;
        float s0 = 0.f, s1 = 0.f;
        for (int ll = 0; ll < 16; ++ll) {
            s0 += base[ll * D + t];
            s1 += base[ll * D + t + 256];
        }
        float* dst = partial + (size_t)blk * D;
        dst[t] = s0;
        dst[t + 256] = s1;
    }
}

// ---------------- kernel 2: MLP head -> alpha/beta --------------------------
__global__ void head_kernel(const float* __restrict__ partial,
                            const float* __restrict__ W1, const float* __restrict__ b1,
                            const float* __restrict__ ln_g, const float* __restrict__ ln_b,
                            const float* __restrict__ W2, const float* __restrict__ b2,
                            float* __restrict__ ab, float* __restrict__ out_tail) {
    const int b = blockIdx.x;
    const int j = threadIdx.x;   // 0..127
    __shared__ float fm[D];
    __shared__ float red[DH];
    for (int d = j; d < D; d += DH) {
        float s = 0.f;
        const float* p = partial + (size_t)b * 64 * D + d;
        for (int c = 0; c < 64; ++c) s += p[c * D];
        fm[d] = s * (1.0f / (float)L);
    }
    __syncthreads();
    float h = b1[j];
    const vf4* fm4 = (const vf4*)fm;
    #pragma unroll 8
    for (int d4 = 0; d4 < D / 4; ++d4) {
        vf4 f = fm4[d4];
        h = fmaf(f.x, W1[(4 * d4 + 0) * DH + j], h);
        h = fmaf(f.y, W1[(4 * d4 + 1) * DH + j], h);
        h = fmaf(f.z, W1[(4 * d4 + 2) * DH + j], h);
        h = fmaf(f.w, W1[(4 * d4 + 3) * DH + j], h);
    }

    red[j] = h; __syncthreads();
    for (int s = 64; s > 0; s >>= 1) { if (j < s) red[j] += red[j + s]; __syncthreads(); }
    float mu = red[0] * (1.f / (float)DH);
    __syncthreads();
    float hc = h - mu;
    red[j] = hc * hc; __syncthreads();
    for (int s = 64; s > 0; s >>= 1) { if (j < s) red[j] += red[j + s]; __syncthreads(); }
    float var = red[0] * (1.f / (float)DH);
    __syncthreads();

    float hn = hc * rsqrtf(var + 1e-5f) * ln_g[j] + ln_b[j];
    hn = fmaxf(hn, 0.f);

    red[j] = hn * W2[j * 2 + 0]; __syncthreads();
    for (int s = 64; s > 0; s >>= 1) { if (j < s) red[j] += red[j + s]; __syncthreads(); }
    float p0 = red[0];
    __syncthreads();
    red[j] = hn * W2[j * 2 + 1]; __syncthreads();
    for (int s = 64; s > 0; s >>= 1) { if (j < s) red[j] += red[j + s]; __syncthreads(); }
    float p1 = red[0];

    if (j == 0) {
        float a  = 0.00015f / (1.f + expf(-(p0 + b2[0])));
        float be = 0.00015f / (1.f + expf(-(p1 + b2[1])));
        ab[b] = a; ab[8 + b] = be;
        out_tail[b] = a; out_tail[8 + b] = be;
    }
}

// ---------------- kernel 3: vertical blur + elementwise synth ---------------
// grid: B * 64 strips * 2 half-widths = 1024 blocks, 256 threads.
// Thread t owns 2 adjacent columns (vf2). Column-split adds parallelism
// WITHOUT duplicating the register window (window is per-column).
// Symmetric kernel halves vblur FMAs.
__global__ __launch_bounds__(256) void final_kernel(
        const float* __restrict__ x_bg, const float* __restrict__ noise,
        const float* __restrict__ hmask, const float* __restrict__ ab,
        float* __restrict__ out, BlurW kw) {
    int blk = blockIdx.x;            // 0..1023
    int b   = blk >> 7;
    int rem = blk & 127;
    int s   = rem >> 1;              // strip 0..63
    int wj  = rem & 1;
    int h0  = s * TH;
    int t   = threadIdx.x;           // 0..255
    int x0  = wj * 512 + 2 * t;      // column pair base

    const float* hmb = hmask + (size_t)b * NPIX + x0;
    const vf2 zero2 = {0.f, 0.f};

    vf2 win[21];
    #pragma unroll
    for (int k = 0; k < 21; ++k) {
        int hy = h0 - 10 + k;
        win[k] = (hy >= 0 && hy < H) ? *(const vf2*)(hmb + (size_t)hy * W) : zero2;
    }

    float alpha = ab[b], beta = ab[8 + b];

    #pragma unroll
    for (int r = 0; r < TH; ++r) {
        vf2 ms = zero2;
        #pragma unroll
        for (int k = 0; k < 10; ++k) {
            float wk = kw.w[k];
            vf2 v1 = win[(r + k) % 21];          // static after unroll
            vf2 v2 = win[(r + 20 - k) % 21];
            ms.x = fmaf(wk, v1.x + v2.x, ms.x);
            ms.y = fmaf(wk, v1.y + v2.y, ms.y);
        }
        {
            vf2 vm = win[(r + 10) % 21];
            ms.x = fmaf(kw.w[10], vm.x, ms.x);
            ms.y = fmaf(kw.w[10], vm.y, ms.y);
        }
        int h = h0 + r;
        #pragma unroll
        for (int c = 0; c < C; ++c) {
            size_t idx = (((size_t)(b * C + c) * H) + h) * W + x0;
            vf2 x = __builtin_nontemporal_load((const vf2*)(x_bg + idx));
            vf2 nz = __builtin_nontemporal_load((const vf2*)(noise + idx));
            vf2 o;
            float sgx = sqrtf(fmaxf(fmaf(alpha, x.x, beta), 1e-7f));
            float sgy = sqrtf(fmaxf(fmaf(alpha, x.y, beta), 1e-7f));
            o.x = fmaf(1.5f * nz.x * sgx, ms.x, x.x);
            o.y = fmaf(1.5f * nz.y * sgy, ms.y, x.y);
            __builtin_nontemporal_store(o, (vf2*)(out + idx));
        }
        if (r < TH - 1) {
            int hy = h0 + r + 11;
            win[r % 21] = (hy < H) ? *(const vf2*)(hmb + (size_t)hy * W) : zero2;
        }
    }
}

extern "C" void kernel_launch(void* const* d_in, const int* in_sizes, int n_in,
                              void* d_out, int out_size, void* d_ws, size_t ws_size,
                              hipStream_t stream) {
    const float* x_bg = (const float*)d_in[0];
    const float* feat = (const float*)d_in[1];
    const float* mask = (const float*)d_in[2];
    const float* noise = (const float*)d_in[3];
    const float* W1 = (const float*)d_in[4];
    const float* b1 = (const float*)d_in[5];
    const float* ln_g = (const float*)d_in[6];
    const float* ln_b = (const float*)d_in[7];
    const float* W2 = (const float*)d_in[8];
    const float* b2 = (const float*)d_in[9];
    float* out = (float*)d_out;

    // ws layout (floats): [0, 262144) partial colsums | [262144, +16) ab | hmask
    float* ws_f = (float*)d_ws;
    float* partial = ws_f;                       // B*64*D = 262144 floats
    float* ab = ws_f + 262144;                   // 16 floats
    float* hmask = ws_f + 262144 + 64;           // B*H*W floats (16B-aligned)

    BlurW kw;
    {
        double g[21], s = 0.0;
        for (int i = 0; i < 21; ++i) { double x = (double)(i - 10); g[i] = exp(-x * x / 50.0); s += g[i]; }
        for (int i = 0; i < 21; ++i) kw.w[i] = (float)(g[i] / s);
    }

    hblur_colsum_kernel<<<8192 + 512, 256, 0, stream>>>(mask, hmask, feat, partial, kw);
    head_kernel<<<B, 128, 0, stream>>>(partial, W1, b1, ln_g, ln_b, W2, b2,
                                       ab, out + NOISY_ELEMS);
    final_kernel<<<B * 64 * 2, 256, 0, stream>>>(x_bg, noise, hmask, ab, out, kw);
}

// Round 8
// 100.759 us; speedup vs baseline: 5.5070x; 1.0388x over previous
//
#include <hip/hip_runtime.h>
#include <math.h>

#define B 8
#define C 3
#define H 1024
#define W 1024
#define L 1024
#define D 512
#define DH 128
#define NPIX (H * W)
#define NOISY_ELEMS (B * C * NPIX) // 25165824
#define TH 16                      // rows per strip in final kernel
#define RPB 8                      // rows per block in hblur
#define LROW 1056                  // padded LDS row (12 halo + 1024 + 12 halo + pad)

typedef float vf2 __attribute__((ext_vector_type(2)));
typedef float vf4 __attribute__((ext_vector_type(4)));

struct BlurW { float w[21]; };

// ---------------- kernel 1: fused horizontal blur (8 rows/block) + colsum ---
// blocks [0, 1024): 8 mask rows each, staged in LDS, vf4 in/out.
// blocks [1024, 1280): colsum of bottleneck_feat, 32 rows/block, vf4.
__global__ __launch_bounds__(256) void hblur_colsum_kernel(
        const float* __restrict__ mask, float* __restrict__ hmask,
        const float* __restrict__ feat, float* __restrict__ partial, BlurW kw) {
    int wgid = blockIdx.x;
    int t = threadIdx.x;             // 256
    __shared__ float Ls[RPB][LROW];  // data at [12 .. 12+W-1], zero halo 10/side

    if (wgid < 1024) {
        size_t row0 = (size_t)wgid * RPB;        // batches contiguous; 8 | 1024
        const float* src = mask + row0 * W;
        #pragma unroll
        for (int r = 0; r < RPB; ++r) {
            vf4 v = __builtin_nontemporal_load((const vf4*)(src + (size_t)r * W) + t);
            *(vf4*)&Ls[r][12 + 4 * t] = v;
        }
        if (t < RPB * 10) {
            int r = t / 10, i = t - 10 * r;
            Ls[r][2 + i] = 0.f;
            Ls[r][12 + W + i] = 0.f;
        }
        __syncthreads();
        float* dst = hmask + row0 * W;
        #pragma unroll
        for (int r = 0; r < RPB; ++r) {
            float v[28];
            #pragma unroll
            for (int j = 0; j < 7; ++j) {
                vf4 q = *(const vf4*)&Ls[r][4 * t + 4 * j];
                v[4 * j] = q.x; v[4 * j + 1] = q.y; v[4 * j + 2] = q.z; v[4 * j + 3] = q.w;
            }
            vf4 o;
            #pragma unroll
            for (int i = 0; i < 4; ++i) {
                float acc = 0.f;
                #pragma unroll
                for (int k = 0; k < 10; ++k)
                    acc = fmaf(kw.w[k], v[i + 2 + k] + v[i + 22 - k], acc);
                o[i] = fmaf(kw.w[10], v[i + 12], acc);
            }
            __builtin_nontemporal_store(o, (vf4*)(dst + (size_t)r * W) + t);
        }
    } else {
        int blk = wgid - 1024;       // 0..255
        int b = blk >> 5, chunk = blk & 31;      // 32 rows per chunk
        int d4 = (t & 127) * 4;
        int half = t >> 7;
        const float* base = feat + (size_t)b * (L * D)
                          + (size_t)(chunk * 32 + half * 16) * D + d4;
        vf4 s = {0.f, 0.f, 0.f, 0.f};
        #pragma unroll
        for (int ll = 0; ll < 16; ++ll) {
            vf4 v = *(const vf4*)(base + (size_t)ll * D);
            s.x += v.x; s.y += v.y; s.z += v.z; s.w += v.w;
        }
        // group g = chunk*2 + half in [0,64); head reads stride-512 over g.
        float* dst = partial + ((size_t)(b * 64 + chunk * 2 + half)) * 512 + d4;
        *(vf4*)dst = s;
    }
}

// ---------------- kernel 2: MLP head -> alpha/beta --------------------------
__global__ void head_kernel(const float* __restrict__ partial,
                            const float* __restrict__ W1, const float* __restrict__ b1,
                            const float* __restrict__ ln_g, const float* __restrict__ ln_b,
                            const float* __restrict__ W2, const float* __restrict__ b2,
                            float* __restrict__ ab, float* __restrict__ out_tail) {
    const int b = blockIdx.x;
    const int j = threadIdx.x;   // 0..127
    __shared__ float fm[D];
    __shared__ float red[DH];
    for (int d = j; d < D; d += DH) {
        float s = 0.f;
        const float* p = partial + (size_t)b * 64 * D + d;
        for (int c = 0; c < 64; ++c) s += p[c * D];
        fm[d] = s * (1.0f / (float)L);
    }
    __syncthreads();
    float h = b1[j];
    const vf4* fm4 = (const vf4*)fm;
    #pragma unroll 8
    for (int d4 = 0; d4 < D / 4; ++d4) {
        vf4 f = fm4[d4];
        h = fmaf(f.x, W1[(4 * d4 + 0) * DH + j], h);
        h = fmaf(f.y, W1[(4 * d4 + 1) * DH + j], h);
        h = fmaf(f.z, W1[(4 * d4 + 2) * DH + j], h);
        h = fmaf(f.w, W1[(4 * d4 + 3) * DH + j], h);
    }

    red[j] = h; __syncthreads();
    for (int s = 64; s > 0; s >>= 1) { if (j < s) red[j] += red[j + s]; __syncthreads(); }
    float mu = red[0] * (1.f / (float)DH);
    __syncthreads();
    float hc = h - mu;
    red[j] = hc * hc; __syncthreads();
    for (int s = 64; s > 0; s >>= 1) { if (j < s) red[j] += red[j + s]; __syncthreads(); }
    float var = red[0] * (1.f / (float)DH);
    __syncthreads();

    float hn = hc * rsqrtf(var + 1e-5f) * ln_g[j] + ln_b[j];
    hn = fmaxf(hn, 0.f);

    red[j] = hn * W2[j * 2 + 0]; __syncthreads();
    for (int s = 64; s > 0; s >>= 1) { if (j < s) red[j] += red[j + s]; __syncthreads(); }
    float p0 = red[0];
    __syncthreads();
    red[j] = hn * W2[j * 2 + 1]; __syncthreads();
    for (int s = 64; s > 0; s >>= 1) { if (j < s) red[j] += red[j + s]; __syncthreads(); }
    float p1 = red[0];

    if (j == 0) {
        float a  = 0.00015f / (1.f + expf(-(p0 + b2[0])));
        float be = 0.00015f / (1.f + expf(-(p1 + b2[1])));
        ab[b] = a; ab[8 + b] = be;
        out_tail[b] = a; out_tail[8 + b] = be;
    }
}

// ---------------- kernel 3: vertical blur + elementwise synth ---------------
// grid: B * 64 strips * 2 half-widths = 1024 blocks, 256 threads, vf2/thread.
// Phase 1: ms[16] = vblur of strip, incremental accumulation over 36 hmask
//          rows (1 live row; all indices literal -> registers).
// Phase 2: 3 sequential channel passes, each streaming only x[c],n[c],out[c]
//          with 16 independent iterations (deep MLP, few DRAM streams).
__global__ __launch_bounds__(256) void final_kernel(
        const float* __restrict__ x_bg, const float* __restrict__ noise,
        const float* __restrict__ hmask, const float* __restrict__ ab,
        float* __restrict__ out, BlurW kw) {
    int blk = blockIdx.x;            // 0..1023
    int b   = blk >> 7;
    int rem = blk & 127;
    int s   = rem >> 1;              // strip 0..63
    int wj  = rem & 1;
    int h0  = s * TH;
    int t   = threadIdx.x;           // 0..255
    int x0  = wj * 512 + 2 * t;      // column pair base

    const float* hmb = hmask + (size_t)b * NPIX + x0;
    const vf2 zero2 = {0.f, 0.f};

    vf2 ms[TH];
    #pragma unroll
    for (int r = 0; r < TH; ++r) ms[r] = zero2;

    #pragma unroll
    for (int k = 0; k < TH + 20; ++k) {          // 36 rows: h0-10 .. h0+25
        int hy = h0 - 10 + k;
        vf2 wv = (hy >= 0 && hy < H) ? *(const vf2*)(hmb + (size_t)hy * W) : zero2;
        #pragma unroll
        for (int r = 0; r < TH; ++r) {
            int dk = k - r;                      // compile-time per (k,r)
            if (dk >= 0 && dk < 21) {
                ms[r].x = fmaf(kw.w[dk], wv.x, ms[r].x);
                ms[r].y = fmaf(kw.w[dk], wv.y, ms[r].y);
            }
        }
    }

    float alpha = ab[b], beta = ab[8 + b];

    #pragma unroll
    for (int c = 0; c < C; ++c) {
        const float* xb = x_bg  + (((size_t)(b * C + c) * H) + h0) * W + x0;
        const float* nb = noise + (((size_t)(b * C + c) * H) + h0) * W + x0;
        float*       ob = out   + (((size_t)(b * C + c) * H) + h0) * W + x0;
        #pragma unroll
        for (int r = 0; r < TH; ++r) {
            vf2 x  = __builtin_nontemporal_load((const vf2*)(xb + (size_t)r * W));
            vf2 nz = __builtin_nontemporal_load((const vf2*)(nb + (size_t)r * W));
            vf2 o;
            float sgx = sqrtf(fmaxf(fmaf(alpha, x.x, beta), 1e-7f));
            float sgy = sqrtf(fmaxf(fmaf(alpha, x.y, beta), 1e-7f));
            o.x = fmaf(1.5f * nz.x * sgx, ms[r].x, x.x);
            o.y = fmaf(1.5f * nz.y * sgy, ms[r].y, x.y);
            *(vf2*)(ob + (size_t)r * W) = o;     // plain store (nt A/B)
        }
    }
}

extern "C" void kernel_launch(void* const* d_in, const int* in_sizes, int n_in,
                              void* d_out, int out_size, void* d_ws, size_t ws_size,
                              hipStream_t stream) {
    const float* x_bg = (const float*)d_in[0];
    const float* feat = (const float*)d_in[1];
    const float* mask = (const float*)d_in[2];
    const float* noise = (const float*)d_in[3];
    const float* W1 = (const float*)d_in[4];
    const float* b1 = (const float*)d_in[5];
    const float* ln_g = (const float*)d_in[6];
    const float* ln_b = (const float*)d_in[7];
    const float* W2 = (const float*)d_in[8];
    const float* b2 = (const float*)d_in[9];
    float* out = (float*)d_out;

    // ws layout (floats): [0, 262144) partial colsums | [262144, +16) ab | hmask
    float* ws_f = (float*)d_ws;
    float* partial = ws_f;                       // B*64*512 = 262144 floats
    float* ab = ws_f + 262144;                   // 16 floats
    float* hmask = ws_f + 262144 + 64;           // B*H*W floats (16B-aligned)

    BlurW kw;
    {
        double g[21], s = 0.0;
        for (int i = 0; i < 21; ++i) { double x = (double)(i - 10); g[i] = exp(-x * x / 50.0); s += g[i]; }
        for (int i = 0; i < 21; ++i) kw.w[i] = (float)(g[i] / s);
    }

    hblur_colsum_kernel<<<1024 + 256, 256, 0, stream>>>(mask, hmask, feat, partial, kw);
    head_kernel<<<B, 128, 0, stream>>>(partial, W1, b1, ln_g, ln_b, W2, b2,
                                       ab, out + NOISY_ELEMS);
    final_kernel<<<B * 64 * 2, 256, 0, stream>>>(x_bg, noise, hmask, ab, out, kw);
}